// Round 5
// baseline (646.667 us; speedup 1.0000x reference)
//
#include <hip/hip_runtime.h>
#include <hip/hip_cooperative_groups.h>
#include <hip/hip_bf16.h>
#include <hip/hip_fp16.h>

#define EPS 1e-8f
#define PI_F 3.14159265358979323846f

namespace cg = cooperative_groups;

typedef _Float16 half8 __attribute__((ext_vector_type(8)));
typedef float f32x4 __attribute__((ext_vector_type(4)));
typedef float f32x2 __attribute__((ext_vector_type(2)));

__device__ __forceinline__ float gelu_exact(float v) {
    return 0.5f * v * (1.0f + erff(v * 0.70710678118654752f));
}

// ---------------------------------------------------------------------------
// Phase bodies (shared between the fused cooperative kernel and the 5-kernel
// fallback path). All arithmetic identical to the round-1/round-4 versions.
// ---------------------------------------------------------------------------

// --- phase 0: embed_w fp32 -> fragment-ordered fp16 hi/lo tiles -------------
// Wth/Wtl [g(4)][kt(8)][r(128)][k(32)]; row order interleaves d so one lane
// owns pair (d0,d0+1): r = (dl>>5)*64 + ((dl&1)+2*h12)*16 + ((dl&31)>>1).
// Also zero-inits XMsum/YMsum/pooled (contiguous 49152 floats).
__device__ __forceinline__ void convert_body(
    int idx, const float* __restrict__ W,
    _Float16* __restrict__ Wth, _Float16* __restrict__ Wtl,
    float* __restrict__ zero_base)
{
    if (idx < 49152) zero_base[idx] = 0.f;
    int col = idx & 511, k = idx >> 9;
    int d   = col & 255;
    int g   = d >> 6;
    int dl  = d & 63;
    int h12 = col >> 8;
    int r   = (dl >> 5) * 64 + ((dl & 1) + 2 * h12) * 16 + ((dl & 31) >> 1);
    int kt  = k >> 5, ko = k & 31;
    float f = W[k * 512 + col];
    _Float16 h = (_Float16)f;
    int o = ((g * 8 + kt) * 128 + r) * 32 + ko;
    Wth[o] = h;
    Wtl[o] = (_Float16)(f - (float)h);
}

// --- phase 1: one 128m x 128n embed-GEMM unit (round-1 structure) ----------
// A staged reg->cvt(fp16 hi/lo)->LDS, 2 barriers/kt; B fragments from L2;
// 3-pass fp16 split (Ah*Bh + Ah*Bl + Al*Bh); fused polar transform epilogue
// with packed-fp8 4B stores and fp32 mean atomics.
__device__ __forceinline__ void gemm_unit(
    int id, int tid, _Float16* Ah, _Float16* Al,
    const float* __restrict__ x,
    const _Float16* __restrict__ Wth, const _Float16* __restrict__ Wtl,
    const float* __restrict__ bias,
    unsigned short* __restrict__ XY8,
    float* __restrict__ XMsum, float* __restrict__ YMsum)
{
    const int wave = tid >> 6;
    const int lane = tid & 63;
    const int wm   = wave >> 1;              // m-half of the 128 rows
    const int wn   = wave & 1;               // n-half of the 128 B-rows
    const int xcd  = id & 7;
    const int s    = id >> 3;
    const int g    = s & 3;                  // d-range [64g, 64g+64)
    const int mt   = (s >> 2) * 8 + xcd;     // 0..511
    const int m0   = mt * 128;
    const int q    = lane >> 4, ln = lane & 15;

    f32x4 acc[4][4];
#pragma unroll
    for (int mi = 0; mi < 4; ++mi)
#pragma unroll
        for (int nt = 0; nt < 4; ++nt)
            acc[mi][nt] = (f32x4){0.f, 0.f, 0.f, 0.f};

    const _Float16* wb = Wth + (size_t)g * 32768 + (wn * 64 + ln) * 32 + q * 8;
    const _Float16* wl = Wtl + (size_t)g * 32768 + (wn * 64 + ln) * 32 + q * 8;

#pragma unroll 1
    for (int kt = 0; kt < 8; ++kt) {
        // B fragments from L2, issued before the barrier (latency overlaps it)
        half8 bh[4], bl[4];
#pragma unroll
        for (int nt = 0; nt < 4; ++nt) {
            bh[nt] = *(const half8*)(wb + kt * 4096 + nt * 512);
            bl[nt] = *(const half8*)(wl + kt * 4096 + nt * 512);
        }
        __syncthreads();
        // stage A tile [128 m][32 k]: fp32 -> fp16 hi + lo residual
#pragma unroll
        for (int L = 0; L < 2; ++L) {
            int idx2 = L * 256 + tid;
            int r = idx2 >> 2, cq = idx2 & 3;
            const float* src = x + (size_t)(m0 + r) * 256 + kt * 32 + cq * 8;
            const float4 f0 = *(const float4*)(src);
            const float4 f1 = *(const float4*)(src + 4);
            half8 hh, ll;
            hh[0] = (_Float16)f0.x; ll[0] = (_Float16)(f0.x - (float)hh[0]);
            hh[1] = (_Float16)f0.y; ll[1] = (_Float16)(f0.y - (float)hh[1]);
            hh[2] = (_Float16)f0.z; ll[2] = (_Float16)(f0.z - (float)hh[2]);
            hh[3] = (_Float16)f0.w; ll[3] = (_Float16)(f0.w - (float)hh[3]);
            hh[4] = (_Float16)f1.x; ll[4] = (_Float16)(f1.x - (float)hh[4]);
            hh[5] = (_Float16)f1.y; ll[5] = (_Float16)(f1.y - (float)hh[5]);
            hh[6] = (_Float16)f1.z; ll[6] = (_Float16)(f1.z - (float)hh[6]);
            hh[7] = (_Float16)f1.w; ll[7] = (_Float16)(f1.w - (float)hh[7]);
            int pos = cq ^ ((r >> 1) & 3);
            *(half8*)&Ah[r * 32 + pos * 8] = hh;
            *(half8*)&Al[r * 32 + pos * 8] = ll;
        }
        __syncthreads();

        half8 am[4];
#pragma unroll
        for (int mi = 0; mi < 4; ++mi) {
            int row = wm * 64 + mi * 16 + ln;
            am[mi] = *(const half8*)&Ah[row * 32 + (q ^ ((row >> 1) & 3)) * 8];
        }
        // pass 1: Ah*Bh
#pragma unroll
        for (int mi = 0; mi < 4; ++mi)
#pragma unroll
            for (int nt = 0; nt < 4; ++nt)
                acc[mi][nt] = __builtin_amdgcn_mfma_f32_16x16x32_f16(am[mi], bh[nt], acc[mi][nt], 0, 0, 0);
        // pass 2: Ah*Bl
#pragma unroll
        for (int mi = 0; mi < 4; ++mi)
#pragma unroll
            for (int nt = 0; nt < 4; ++nt)
                acc[mi][nt] = __builtin_amdgcn_mfma_f32_16x16x32_f16(am[mi], bl[nt], acc[mi][nt], 0, 0, 0);
        // pass 3: Al*Bh
#pragma unroll
        for (int mi = 0; mi < 4; ++mi) {
            int row = wm * 64 + mi * 16 + ln;
            half8 alv = *(const half8*)&Al[row * 32 + (q ^ ((row >> 1) & 3)) * 8];
#pragma unroll
            for (int nt = 0; nt < 4; ++nt)
                acc[mi][nt] = __builtin_amdgcn_mfma_f32_16x16x32_f16(alv, bh[nt], acc[mi][nt], 0, 0, 0);
        }
    }

    // epilogue: acc[mi][0]=h1(d0), [1]=h1(d0+1), [2]=h2(d0), [3]=h2(d0+1),
    // d0 = g*64 + wn*32 + 2*ln. C/D: col=lane&15, row=(lane>>4)*4+reg [m89]
    const int d0 = g * 64 + wn * 32 + 2 * ln;
    const int b  = m0 >> 10;
    const float b1_0 = bias[d0],       b1_1 = bias[d0 + 1];
    const float b2_0 = bias[256 + d0], b2_1 = bias[256 + d0 + 1];
    float sx0 = 0.f, sy0 = 0.f, sx1 = 0.f, sy1 = 0.f;
#pragma unroll
    for (int mi = 0; mi < 4; ++mi) {
#pragma unroll
        for (int i = 0; i < 4; ++i) {
            const int row = m0 + wm * 64 + mi * 16 + q * 4 + i;
            const float h1a = acc[mi][0][i] + b1_0;
            const float h2a = acc[mi][2][i] + b2_0;
            const float rra = fabsf(h1a) + 0.1f;
            float sva, cva;
            __sincosf(PI_F * h2a, &sva, &cva);
            const float xca = rra * cva, yca = rra * sva;
            const float h1b = acc[mi][1][i] + b1_1;
            const float h2b = acc[mi][3][i] + b2_1;
            const float rrb = fabsf(h1b) + 0.1f;
            float svb, cvb;
            __sincosf(PI_F * h2b, &svb, &cvb);
            const float xcb = rrb * cvb, ycb = rrb * svb;
            int pk = __builtin_amdgcn_cvt_pk_fp8_f32(xca, yca, 0, false);
            pk = __builtin_amdgcn_cvt_pk_fp8_f32(xcb, ycb, pk, true);
            *(unsigned int*)(XY8 + (size_t)row * 256 + d0) = (unsigned int)pk;
            sx0 += xca; sy0 += yca;
            sx1 += xcb; sy1 += ycb;
        }
    }
    sx0 += __shfl_down(sx0, 32); sx0 += __shfl_down(sx0, 16);
    sy0 += __shfl_down(sy0, 32); sy0 += __shfl_down(sy0, 16);
    sx1 += __shfl_down(sx1, 32); sx1 += __shfl_down(sx1, 16);
    sy1 += __shfl_down(sy1, 32); sy1 += __shfl_down(sy1, 16);
    if (lane < 16) {
        atomicAdd(&XMsum[b * 256 + d0], sx0);
        atomicAdd(&YMsum[b * 256 + d0], sy0);
        atomicAdd(&XMsum[b * 256 + d0 + 1], sx1);
        atomicAdd(&YMsum[b * 256 + d0 + 1], sy1);
    }
}

// --- phase 2: 8-layer recurrence on the means ------------------------------
// sm layout (floats): mw1@0[256] mb1@256 mw2@512 pb1@768 pw1@1024[512]
// pw2@1536[512] mb2@2048[8] pb2@2056[16]  (8288 B)
__device__ __forceinline__ void layers_body(
    int bid, int tid, float* sm,
    const float* __restrict__ XMsum, const float* __restrict__ YMsum,
    const float* __restrict__ mw1, const float* __restrict__ mb1,
    const float* __restrict__ mw2, const float* __restrict__ mb2,
    const float* __restrict__ pw1, const float* __restrict__ pb1,
    const float* __restrict__ pw2, const float* __restrict__ pb2,
    float* __restrict__ DX, float* __restrict__ DY)
{
    sm[tid] = mw1[tid]; sm[256 + tid] = mb1[tid];
    sm[512 + tid] = mw2[tid]; sm[768 + tid] = pb1[tid];
    sm[1024 + tid] = pw1[tid]; sm[1280 + tid] = pw1[256 + tid];
    sm[1536 + tid] = pw2[tid]; sm[1792 + tid] = pw2[256 + tid];
    if (tid < 8)  sm[2048 + tid] = mb2[tid];
    if (tid < 16) sm[2056 + tid] = pb2[tid];
    __syncthreads();

    const int gid = bid * 256 + tid;
    const int idx = gid >> 3;                 // (b,d), 16384
    const int sub = gid & 7;                  // k-eighth
    float xm = XMsum[idx] * (1.0f / 1024.0f);
    float ym = YMsum[idx] * (1.0f / 1024.0f);
    float dxa = 0.f, dya = 0.f;
#pragma unroll 1
    for (int i = 0; i < 8; ++i) {
        float r2    = xm * xm + ym * ym;
        float r_agg = sqrtf(r2 + EPS);
        float hyp   = sqrtf(r2);
        float inv   = hyp > 0.f ? 1.0f / hyp : 0.f;
        float st    = ym * inv;
        float ct    = hyp > 0.f ? xm * inv : 1.0f;
        float log_r = logf(r_agg + EPS);
        float lr = 0.f, p0 = 0.f, p1 = 0.f;
#pragma unroll
        for (int k4 = 0; k4 < 4; ++k4) {
            int k = sub * 4 + k4;
            float hm = gelu_exact(log_r * sm[i * 32 + k] + sm[256 + i * 32 + k]);
            lr += hm * sm[512 + i * 32 + k];
            float hp = gelu_exact(st * sm[1024 + i * 64 + k] + ct * sm[1024 + i * 64 + 32 + k] + sm[768 + i * 32 + k]);
            p0 += hp * sm[1536 + i * 64 + 2 * k + 0];
            p1 += hp * sm[1536 + i * 64 + 2 * k + 1];
        }
        lr += __shfl_xor(lr, 1); lr += __shfl_xor(lr, 2); lr += __shfl_xor(lr, 4);
        p0 += __shfl_xor(p0, 1); p0 += __shfl_xor(p0, 2); p0 += __shfl_xor(p0, 4);
        p1 += __shfl_xor(p1, 1); p1 += __shfl_xor(p1, 2); p1 += __shfl_xor(p1, 4);
        lr += sm[2048 + i];
        p0 += sm[2056 + i * 2 + 0];
        p1 += sm[2056 + i * 2 + 1];
        float r_trans = expf(lr);
        float hp2  = sqrtf(p0 * p0 + p1 * p1);
        float invp = hp2 > 0.f ? 1.0f / hp2 : 0.f;
        float ctt  = hp2 > 0.f ? p1 * invp : 1.0f;
        float stt  = p0 * invp;
        float dx = r_trans * ctt;
        float dy = r_trans * stt;
        dxa += dx; dya += dy; xm += dx; ym += dy;
    }
    if (sub == 0) { DX[idx] = dxa; DY[idx] = dya; }
}

// --- phase 3: pooled[b,d] += sum_s sqrt((xc+DX)^2 + (yc+DY)^2 + EPS) -------
__device__ __forceinline__ void pool_body(
    int b, int sc, int tid, float (*red)[9],
    const unsigned short* __restrict__ XY8,
    const float* __restrict__ DX, const float* __restrict__ DY,
    float* __restrict__ pooled)
{
    const int dg = tid & 31;           // d-group: d = dg*8 .. dg*8+7
    const int sh = tid >> 5;           // s-subchunk (16 rows each)
    const int d0 = dg * 8;
    float dxv[8], dyv[8], s[8];
#pragma unroll
    for (int j = 0; j < 8; ++j) {
        dxv[j] = DX[b * 256 + d0 + j];
        dyv[j] = DY[b * 256 + d0 + j];
        s[j] = 0.f;
    }
    const int r0 = sc * 128 + sh * 16;
    const size_t base = ((size_t)b * 1024 + r0) * 256 + d0;
#pragma unroll 4
    for (int i = 0; i < 16; ++i) {
        const int4 v = *(const int4*)(XY8 + base + (size_t)i * 256);
        const int wv[4] = {v.x, v.y, v.z, v.w};
#pragma unroll
        for (int w = 0; w < 4; ++w) {
            f32x2 pa = __builtin_amdgcn_cvt_pk_f32_fp8(wv[w], false);
            f32x2 pb = __builtin_amdgcn_cvt_pk_f32_fp8(wv[w], true);
            float xa = pa[0] + dxv[2 * w],     ya = pa[1] + dyv[2 * w];
            float xb = pb[0] + dxv[2 * w + 1], yb = pb[1] + dyv[2 * w + 1];
            s[2 * w]     += sqrtf(xa * xa + ya * ya + EPS);
            s[2 * w + 1] += sqrtf(xb * xb + yb * yb + EPS);
        }
    }
#pragma unroll
    for (int j = 0; j < 8; ++j) red[tid][j] = s[j];
    __syncthreads();
    if (tid < 32) {
#pragma unroll
        for (int j = 0; j < 8; ++j) {
            float t = 0.f;
#pragma unroll
            for (int c = 0; c < 8; ++c) t += red[c * 32 + tid][j];
            atomicAdd(&pooled[b * 256 + tid * 8 + j], t);
        }
    }
}

// --- phase 4: classifier ---------------------------------------------------
// smf layout (floats): pl@0[256] part@256[256] hd@512[32]
__device__ __forceinline__ void cls_body(
    int b, int yc, int tid, float* smf,
    const float* __restrict__ pooled,
    const float* __restrict__ w1, const float* __restrict__ b1,
    const float* __restrict__ w2, const float* __restrict__ b2,
    float* __restrict__ out)
{
    smf[tid] = pooled[b * 256 + tid] * (1.0f / 1024.0f);
    __syncthreads();
    const int hu = tid & 31, kc = tid >> 5;
    float a = 0.f;
    for (int k = kc * 32; k < kc * 32 + 32; ++k) a += smf[k] * w1[k * 32 + hu];
    smf[256 + kc * 32 + hu] = a;
    __syncthreads();
    if (tid < 32) {
        float s = b1[tid];
#pragma unroll
        for (int c = 0; c < 8; ++c) s += smf[256 + c * 32 + tid];
        smf[512 + tid] = gelu_exact(s);
    }
    __syncthreads();
    const int n0 = yc * 250;
    const int nend = (n0 + 250 < 1000) ? n0 + 250 : 1000;
    for (int n = n0 + tid; n < nend; n += 256) {
        float s = b2[n];
#pragma unroll
        for (int k = 0; k < 32; ++k) s += smf[512 + k] * w2[k * 1000 + n];
        out[b * 1000 + n] = s;
    }
}

// ---------------------------------------------------------------------------
// Fused cooperative kernel: all 5 phases, grid.sync() between them.
// 1024 blocks x 256 thr, 4 blocks/CU co-resident (VGPR<=128, LDS 16KB).
// Phase 1 runs 2 gemm units/block: (bid) and (bid+1024) -> same XCD, same g,
// so the x L2-reuse swizzle is preserved.
// ---------------------------------------------------------------------------
__global__ __launch_bounds__(256, 4) void fused_all(
    const float* __restrict__ x, const float* __restrict__ embed_w,
    const float* __restrict__ embed_b,
    const float* __restrict__ mw1, const float* __restrict__ mb1,
    const float* __restrict__ mw2, const float* __restrict__ mb2,
    const float* __restrict__ pw1, const float* __restrict__ pb1,
    const float* __restrict__ pw2, const float* __restrict__ pb2,
    const float* __restrict__ cw1, const float* __restrict__ cb1,
    const float* __restrict__ cw2, const float* __restrict__ cb2,
    float* __restrict__ out,
    unsigned short* __restrict__ XY8,
    _Float16* __restrict__ Wth, _Float16* __restrict__ Wtl,
    float* __restrict__ XMsum, float* __restrict__ YMsum,
    float* __restrict__ pooled, float* __restrict__ DX, float* __restrict__ DY)
{
    cg::grid_group grid = cg::this_grid();
    __shared__ __attribute__((aligned(16))) char smem[16384];
    const int bid = blockIdx.x, tid = threadIdx.x;

    // phase 0: convertW + zero-init (131072 items; bids >= 512 idle)
    {
        int idx = bid * 256 + tid;
        if (idx < 131072) convert_body(idx, embed_w, Wth, Wtl, XMsum);
    }
    grid.sync();

    // phase 1: embed GEMM, 2 units per block
    {
        _Float16* Ah = (_Float16*)smem;
        _Float16* Al = Ah + 4096;
#pragma unroll 1
        for (int u = 0; u < 2; ++u)
            gemm_unit(bid + u * 1024, tid, Ah, Al, x, Wth, Wtl, embed_b, XY8, XMsum, YMsum);
    }
    grid.sync();

    // phase 2: 8-layer recurrence (512 active blocks)
    if (bid < 512)
        layers_body(bid, tid, (float*)smem, XMsum, YMsum,
                    mw1, mb1, mw2, mb2, pw1, pb1, pw2, pb2, DX, DY);
    grid.sync();

    // phase 3: pool (512 active blocks: b = bid>>3, sc = bid&7)
    if (bid < 512)
        pool_body(bid >> 3, bid & 7, tid, (float(*)[9])smem, XY8, DX, DY, pooled);
    grid.sync();

    // phase 4: classifier (256 active blocks: b = bid>>2, yc = bid&3)
    if (bid < 256)
        cls_body(bid >> 2, bid & 3, tid, (float*)smem, pooled, cw1, cb1, cw2, cb2, out);
}

// ---------------------------------------------------------------------------
// Fallback wrappers (5-kernel path, identical math) in case cooperative
// launch is rejected (capture-unsupported / occupancy).
// ---------------------------------------------------------------------------
__global__ __launch_bounds__(256) void convertW_k(
    const float* __restrict__ W, _Float16* __restrict__ Wth,
    _Float16* __restrict__ Wtl, float* __restrict__ zero_base)
{
    convert_body(blockIdx.x * 256 + threadIdx.x, W, Wth, Wtl, zero_base);
}

__global__ __launch_bounds__(256, 4) void gemm_k(
    const float* __restrict__ x, const _Float16* __restrict__ Wth,
    const _Float16* __restrict__ Wtl, const float* __restrict__ bias,
    unsigned short* __restrict__ XY8, float* __restrict__ XMsum,
    float* __restrict__ YMsum)
{
    __shared__ __attribute__((aligned(16))) _Float16 Ah[4096], Al[4096];
    gemm_unit(blockIdx.x, threadIdx.x, Ah, Al, x, Wth, Wtl, bias, XY8, XMsum, YMsum);
}

__global__ __launch_bounds__(256) void layers_k(
    const float* __restrict__ XMsum, const float* __restrict__ YMsum,
    const float* __restrict__ mw1, const float* __restrict__ mb1,
    const float* __restrict__ mw2, const float* __restrict__ mb2,
    const float* __restrict__ pw1, const float* __restrict__ pb1,
    const float* __restrict__ pw2, const float* __restrict__ pb2,
    float* __restrict__ DX, float* __restrict__ DY)
{
    __shared__ float sm[2072];
    layers_body(blockIdx.x, threadIdx.x, sm, XMsum, YMsum,
                mw1, mb1, mw2, mb2, pw1, pb1, pw2, pb2, DX, DY);
}

__global__ __launch_bounds__(256) void pool_k(
    const unsigned short* __restrict__ XY8,
    const float* __restrict__ DX, const float* __restrict__ DY,
    float* __restrict__ pooled)
{
    __shared__ float red[256][9];
    pool_body(blockIdx.x, blockIdx.y, threadIdx.x, red, XY8, DX, DY, pooled);
}

__global__ __launch_bounds__(256) void cls_k(
    const float* __restrict__ pooled,
    const float* __restrict__ w1, const float* __restrict__ b1,
    const float* __restrict__ w2, const float* __restrict__ b2,
    float* __restrict__ out)
{
    __shared__ float smf[544];
    cls_body(blockIdx.x, blockIdx.y, threadIdx.x, smf, pooled, w1, b1, w2, b2, out);
}

// ---------------------------------------------------------------------------
extern "C" void kernel_launch(void* const* d_in, const int* in_sizes, int n_in,
                              void* d_out, int out_size, void* d_ws, size_t ws_size,
                              hipStream_t stream)
{
    const float* x       = (const float*)d_in[0];
    const float* embed_w = (const float*)d_in[1];
    const float* embed_b = (const float*)d_in[2];
    const float* mag_w1  = (const float*)d_in[3];
    const float* mag_b1  = (const float*)d_in[4];
    const float* mag_w2  = (const float*)d_in[5];
    const float* mag_b2  = (const float*)d_in[6];
    const float* ph_w1   = (const float*)d_in[7];
    const float* ph_b1   = (const float*)d_in[8];
    const float* ph_w2   = (const float*)d_in[9];
    const float* ph_b2   = (const float*)d_in[10];
    const float* cls_w1  = (const float*)d_in[11];
    const float* cls_b1  = (const float*)d_in[12];
    const float* cls_w2  = (const float*)d_in[13];
    const float* cls_b2  = (const float*)d_in[14];
    float* out = (float*)d_out;

    char* ws = (char*)d_ws;
    unsigned short* XY8 = (unsigned short*)(ws + 0);   // 33554432 B (fp8 pairs)
    _Float16* Wth = (_Float16*)(ws + 33554432);        // 262144
    _Float16* Wtl = (_Float16*)(ws + 33816576);        // 262144
    float* XMsum  = (float*)(ws + 34078720);           // 65536
    float* YMsum  = (float*)(ws + 34144256);           // 65536
    float* pooled = (float*)(ws + 34209792);           // 65536
    float* DX     = (float*)(ws + 34275328);           // 65536
    float* DY     = (float*)(ws + 34340864);           // 65536

    void* args[] = {
        (void*)&x, (void*)&embed_w, (void*)&embed_b,
        (void*)&mag_w1, (void*)&mag_b1, (void*)&mag_w2, (void*)&mag_b2,
        (void*)&ph_w1, (void*)&ph_b1, (void*)&ph_w2, (void*)&ph_b2,
        (void*)&cls_w1, (void*)&cls_b1, (void*)&cls_w2, (void*)&cls_b2,
        (void*)&out,
        (void*)&XY8, (void*)&Wth, (void*)&Wtl,
        (void*)&XMsum, (void*)&YMsum, (void*)&pooled, (void*)&DX, (void*)&DY
    };

    hipError_t err = hipLaunchCooperativeKernel(
        (void*)fused_all, dim3(1024), dim3(256), args, 0, stream);

    if (err != hipSuccess) {
        (void)hipGetLastError();   // clear sticky error, fall back to 5-kernel path
        convertW_k<<<512, 256, 0, stream>>>(embed_w, Wth, Wtl, XMsum);
        gemm_k<<<2048, 256, 0, stream>>>(x, Wth, Wtl, embed_b, XY8, XMsum, YMsum);
        layers_k<<<512, 256, 0, stream>>>(XMsum, YMsum, mag_w1, mag_b1, mag_w2, mag_b2,
                                          ph_w1, ph_b1, ph_w2, ph_b2, DX, DY);
        pool_k<<<dim3(64, 8), 256, 0, stream>>>(XY8, DX, DY, pooled);
        cls_k<<<dim3(64, 4), 256, 0, stream>>>(pooled, cls_w1, cls_b1, cls_w2, cls_b2, out);
    }
}

// Round 6
// 209.088 us; speedup vs baseline: 3.0928x; 3.0928x over previous
//
#include <hip/hip_runtime.h>
#include <hip/hip_bf16.h>
#include <hip/hip_fp16.h>

#define EPS 1e-8f
#define PI_F 3.14159265358979323846f

typedef _Float16 half8 __attribute__((ext_vector_type(8)));
typedef float f32x4 __attribute__((ext_vector_type(4)));
typedef float f32x2 __attribute__((ext_vector_type(2)));

__device__ __forceinline__ float gelu_exact(float v) {
    return 0.5f * v * (1.0f + erff(v * 0.70710678118654752f));
}

// ---------------------------------------------------------------------------
// Kernel 0 (verbatim round-1, best measured): embed_w fp32 -> fragment-
// ordered fp16 hi/lo tiles [g(4)][kt(8)][r(128)][k(32)]; also zero-inits
// XMsum/YMsum/pooled (contiguous 49152 floats).
// ---------------------------------------------------------------------------
__global__ void convertW(const float* __restrict__ W,
                         _Float16* __restrict__ Wth, _Float16* __restrict__ Wtl,
                         float* __restrict__ zero_base) {
    int idx = blockIdx.x * 256 + threadIdx.x;   // 0..131071
    if (idx < 49152) zero_base[idx] = 0.f;      // XMsum,YMsum,pooled
    int col = idx & 511, k = idx >> 9;
    int d  = col & 255;
    int g  = d >> 6;
    int dl = d & 63;
    int r  = (dl >> 5) * 64 + ((col >> 8) << 5) + (dl & 31);
    int kt = k >> 5, ko = k & 31;
    float f = W[k * 512 + col];
    _Float16 h = (_Float16)f;
    int o = ((g * 8 + kt) * 128 + r) * 32 + ko;
    Wth[o] = h;
    Wtl[o] = (_Float16)(f - (float)h);
}

// ---------------------------------------------------------------------------
// Kernel 1 (verbatim round-1, best measured 70.2us): embed GEMM, 3-pass fp16
// split, tile 128x128, 2x2 waves, B fragments from L2, A staged via LDS,
// fused polar epilogue (fp8 XY8 stores + fp32 mean atomics).
// ---------------------------------------------------------------------------
__global__ __launch_bounds__(256, 4) void gemm_embed(
    const float* __restrict__ x,
    const _Float16* __restrict__ Wth, const _Float16* __restrict__ Wtl,
    const float* __restrict__ bias,
    unsigned short* __restrict__ XY8,
    float* __restrict__ XMsum, float* __restrict__ YMsum)
{
    __shared__ __attribute__((aligned(16))) _Float16 Ah[4096], Al[4096];
    const int tid  = threadIdx.x;
    const int wave = tid >> 6;
    const int lane = tid & 63;
    const int wm   = wave >> 1;              // m-half of the 128 rows
    const int wn   = wave & 1;               // n-half of the 128 B-rows
    const int id   = blockIdx.x;
    const int xcd  = id & 7;
    const int s    = id >> 3;
    const int g    = s & 3;                  // d-range [64g, 64g+64)
    const int mt   = (s >> 2) * 8 + xcd;     // 0..511
    const int m0   = mt * 128;
    const int q    = lane >> 4, ln = lane & 15;

    f32x4 acc[4][4];
#pragma unroll
    for (int mi = 0; mi < 4; ++mi)
#pragma unroll
        for (int nt = 0; nt < 4; ++nt)
            acc[mi][nt] = (f32x4){0.f, 0.f, 0.f, 0.f};

    for (int kt = 0; kt < 8; ++kt) {
        // ---- B fragments straight from global (L2-resident, 0.5 MB) ----
        half8 bh[4], bl[4];
        {
            const int tbase = (g * 8 + kt) * 4096;
#pragma unroll
            for (int nt = 0; nt < 4; ++nt) {
                int off = tbase + (wn * 64 + nt * 16 + ln) * 32 + q * 8;
                bh[nt] = *(const half8*)(Wth + off);
                bl[nt] = *(const half8*)(Wtl + off);
            }
        }
        __syncthreads();
        // ---- stage A tile [128 m][32 k]: fp32 -> fp16 hi + lo residual ----
#pragma unroll
        for (int L = 0; L < 2; ++L) {
            int idx2 = L * 256 + tid;
            int r = idx2 >> 2, cq = idx2 & 3;
            const float* src = x + (size_t)(m0 + r) * 256 + kt * 32 + cq * 8;
            const float4 f0 = *(const float4*)(src);
            const float4 f1 = *(const float4*)(src + 4);
            half8 hh, ll;
            hh[0] = (_Float16)f0.x; ll[0] = (_Float16)(f0.x - (float)hh[0]);
            hh[1] = (_Float16)f0.y; ll[1] = (_Float16)(f0.y - (float)hh[1]);
            hh[2] = (_Float16)f0.z; ll[2] = (_Float16)(f0.z - (float)hh[2]);
            hh[3] = (_Float16)f0.w; ll[3] = (_Float16)(f0.w - (float)hh[3]);
            hh[4] = (_Float16)f1.x; ll[4] = (_Float16)(f1.x - (float)hh[4]);
            hh[5] = (_Float16)f1.y; ll[5] = (_Float16)(f1.y - (float)hh[5]);
            hh[6] = (_Float16)f1.z; ll[6] = (_Float16)(f1.z - (float)hh[6]);
            hh[7] = (_Float16)f1.w; ll[7] = (_Float16)(f1.w - (float)hh[7]);
            int pos = cq ^ ((r >> 1) & 3);
            *(half8*)&Ah[r * 32 + pos * 8] = hh;
            *(half8*)&Al[r * 32 + pos * 8] = ll;
        }
        __syncthreads();

        // ---- A fragments (rows wm*64 .. wm*64+63) ----
        half8 am[4];
#pragma unroll
        for (int mi = 0; mi < 4; ++mi) {
            int row = wm * 64 + mi * 16 + ln;
            am[mi] = *(const half8*)&Ah[row * 32 + (q ^ ((row >> 1) & 3)) * 8];
        }
        // pass 1: Ah*Bh
#pragma unroll
        for (int mi = 0; mi < 4; ++mi)
#pragma unroll
            for (int nt = 0; nt < 4; ++nt)
                acc[mi][nt] = __builtin_amdgcn_mfma_f32_16x16x32_f16(am[mi], bh[nt], acc[mi][nt], 0, 0, 0);
        // pass 2: Ah*Bl
#pragma unroll
        for (int mi = 0; mi < 4; ++mi)
#pragma unroll
            for (int nt = 0; nt < 4; ++nt)
                acc[mi][nt] = __builtin_amdgcn_mfma_f32_16x16x32_f16(am[mi], bl[nt], acc[mi][nt], 0, 0, 0);
        // pass 3: Al*Bh
#pragma unroll
        for (int mi = 0; mi < 4; ++mi) {
            int row = wm * 64 + mi * 16 + ln;
            half8 alv = *(const half8*)&Al[row * 32 + (q ^ ((row >> 1) & 3)) * 8];
#pragma unroll
            for (int nt = 0; nt < 4; ++nt)
                acc[mi][nt] = __builtin_amdgcn_mfma_f32_16x16x32_f16(alv, bh[nt], acc[mi][nt], 0, 0, 0);
        }
    }

    // ---- epilogue ----
    // B row order: nt=0 -> h1 of d0, nt=1 -> h1 of d1, nt=2 -> h2 of d0,
    // nt=3 -> h2 of d1 where d0 = g*64 + wn*32 + ln, d1 = d0 + 16.
    // C/D layout: col = lane&15, row = (lane>>4)*4 + reg  [m89 verified]
    const int d0 = g * 64 + wn * 32 + ln;
    const int d1 = d0 + 16;
    const int b  = m0 >> 10;
    const float b1_0 = bias[d0],       b1_1 = bias[d1];
    const float b2_0 = bias[256 + d0], b2_1 = bias[256 + d1];
    float sx0 = 0.f, sy0 = 0.f, sx1 = 0.f, sy1 = 0.f;
#pragma unroll
    for (int mi = 0; mi < 4; ++mi) {
#pragma unroll
        for (int i = 0; i < 4; ++i) {
            const int row = m0 + wm * 64 + mi * 16 + q * 4 + i;
            {
                const float h1 = acc[mi][0][i] + b1_0;
                const float h2 = acc[mi][2][i] + b2_0;
                const float rr = fabsf(h1) + 0.1f;
                float sv, cv;
                __sincosf(PI_F * h2, &sv, &cv);
                const float xc = rr * cv, yc = rr * sv;
                int pk = __builtin_amdgcn_cvt_pk_fp8_f32(xc, yc, 0, false);
                XY8[(size_t)row * 256 + d0] = (unsigned short)pk;
                sx0 += xc; sy0 += yc;
            }
            {
                const float h1 = acc[mi][1][i] + b1_1;
                const float h2 = acc[mi][3][i] + b2_1;
                const float rr = fabsf(h1) + 0.1f;
                float sv, cv;
                __sincosf(PI_F * h2, &sv, &cv);
                const float xc = rr * cv, yc = rr * sv;
                int pk = __builtin_amdgcn_cvt_pk_fp8_f32(xc, yc, 0, false);
                XY8[(size_t)row * 256 + d1] = (unsigned short)pk;
                sx1 += xc; sy1 += yc;
            }
        }
    }
    sx0 += __shfl_down(sx0, 32); sx0 += __shfl_down(sx0, 16);
    sy0 += __shfl_down(sy0, 32); sy0 += __shfl_down(sy0, 16);
    sx1 += __shfl_down(sx1, 32); sx1 += __shfl_down(sx1, 16);
    sy1 += __shfl_down(sy1, 32); sy1 += __shfl_down(sy1, 16);
    if (lane < 16) {
        atomicAdd(&XMsum[b * 256 + d0], sx0);
        atomicAdd(&YMsum[b * 256 + d0], sy0);
        atomicAdd(&XMsum[b * 256 + d1], sx1);
        atomicAdd(&YMsum[b * 256 + d1], sy1);
    }
}

// ---------------------------------------------------------------------------
// Kernel 2 (NEW): fused layers + pool. Grid (64 b, 4 d-quarters); each block
// EXCLUSIVELY owns (b, 64 d's) -> DX/DY live in LDS only, pooled written
// with plain stores (no atomics, no zero-init dependency).
// layers phase: identical 8-threads-per-(b,d) shuffle structure and k-order
// as the measured round-1 layers_kernel (bit-identical recurrence); 2 sweeps
// of 256 threads cover 64 d x 8 subs.
// pool phase: thread = (sh 0..31) x (dg 0..7); 32 rows x 8 d each, int4
// fp8-pair loads, red[256][9] tree (pad-9 conflict-free), fixed-order sum
// (pool's cross-chunk order was already nondeterministic via atomics).
// ---------------------------------------------------------------------------
__global__ __launch_bounds__(256) void tail_kernel(
    const float* __restrict__ XMsum, const float* __restrict__ YMsum,
    const float* __restrict__ mw1, const float* __restrict__ mb1,
    const float* __restrict__ mw2, const float* __restrict__ mb2,
    const float* __restrict__ pw1, const float* __restrict__ pb1,
    const float* __restrict__ pw2, const float* __restrict__ pb2,
    const unsigned short* __restrict__ XY8,
    float* __restrict__ pooled)
{
    __shared__ float s_mw1[256], s_mb1[256], s_mw2[256], s_mb2[8];
    __shared__ float s_pw1[512], s_pb1[256], s_pw2[512], s_pb2[16];
    __shared__ float dxl[64], dyl[64];
    __shared__ float red[256][9];
    const int b = blockIdx.x, qd = blockIdx.y, tid = threadIdx.x;

    s_mw1[tid] = mw1[tid]; s_mb1[tid] = mb1[tid];
    s_mw2[tid] = mw2[tid]; s_pb1[tid] = pb1[tid];
    s_pw1[tid] = pw1[tid]; s_pw1[256 + tid] = pw1[256 + tid];
    s_pw2[tid] = pw2[tid]; s_pw2[256 + tid] = pw2[256 + tid];
    if (tid < 8)  s_mb2[tid] = mb2[tid];
    if (tid < 16) s_pb2[tid] = pb2[tid];
    __syncthreads();

    // ---- layers phase: 2 sweeps x 256 threads = 64 d x 8 subs ----
#pragma unroll 1
    for (int it = 0; it < 2; ++it) {
        const int u    = it * 256 + tid;
        const int sub  = u & 7;                    // k-eighth
        const int dloc = u >> 3;                   // 0..63
        const int idx  = b * 256 + qd * 64 + dloc;
        float xm = XMsum[idx] * (1.0f / 1024.0f);
        float ym = YMsum[idx] * (1.0f / 1024.0f);
        float dxa = 0.f, dya = 0.f;
#pragma unroll 1
        for (int i = 0; i < 8; ++i) {
            float r2    = xm * xm + ym * ym;
            float r_agg = sqrtf(r2 + EPS);
            float hyp   = sqrtf(r2);
            float inv   = hyp > 0.f ? 1.0f / hyp : 0.f;
            float st    = ym * inv;
            float ct    = hyp > 0.f ? xm * inv : 1.0f;
            float log_r = logf(r_agg + EPS);
            float lr = 0.f, p0 = 0.f, p1 = 0.f;
#pragma unroll
            for (int k4 = 0; k4 < 4; ++k4) {
                int k = sub * 4 + k4;
                float hm = gelu_exact(log_r * s_mw1[i * 32 + k] + s_mb1[i * 32 + k]);
                lr += hm * s_mw2[i * 32 + k];
                float hp = gelu_exact(st * s_pw1[i * 64 + k] + ct * s_pw1[i * 64 + 32 + k] + s_pb1[i * 32 + k]);
                p0 += hp * s_pw2[i * 64 + 2 * k + 0];
                p1 += hp * s_pw2[i * 64 + 2 * k + 1];
            }
            lr += __shfl_xor(lr, 1); lr += __shfl_xor(lr, 2); lr += __shfl_xor(lr, 4);
            p0 += __shfl_xor(p0, 1); p0 += __shfl_xor(p0, 2); p0 += __shfl_xor(p0, 4);
            p1 += __shfl_xor(p1, 1); p1 += __shfl_xor(p1, 2); p1 += __shfl_xor(p1, 4);
            lr += s_mb2[i];
            p0 += s_pb2[i * 2 + 0];
            p1 += s_pb2[i * 2 + 1];
            float r_trans = expf(lr);
            float hp2  = sqrtf(p0 * p0 + p1 * p1);
            float invp = hp2 > 0.f ? 1.0f / hp2 : 0.f;
            float ctt  = hp2 > 0.f ? p1 * invp : 1.0f;
            float stt  = p0 * invp;
            float dx = r_trans * ctt;
            float dy = r_trans * stt;
            dxa += dx; dya += dy; xm += dx; ym += dy;
        }
        if (sub == 0) { dxl[dloc] = dxa; dyl[dloc] = dya; }
    }
    __syncthreads();

    // ---- pool phase: 64 d x 1024 s per block ----
    {
        const int dg = tid & 7;            // d-octet: d = qd*64 + dg*8 ..+7
        const int sh = tid >> 3;           // 0..31: rows sh*32 .. sh*32+31
        const int d0 = qd * 64 + dg * 8;
        float dxv[8], dyv[8], sacc[8];
#pragma unroll
        for (int j = 0; j < 8; ++j) {
            dxv[j] = dxl[dg * 8 + j];
            dyv[j] = dyl[dg * 8 + j];
            sacc[j] = 0.f;
        }
        const size_t base = ((size_t)b * 1024 + sh * 32) * 256 + d0;
#pragma unroll 4
        for (int i = 0; i < 32; ++i) {
            const int4 v = *(const int4*)(XY8 + base + (size_t)i * 256);
            const int wv[4] = {v.x, v.y, v.z, v.w};
#pragma unroll
            for (int w = 0; w < 4; ++w) {
                f32x2 pa = __builtin_amdgcn_cvt_pk_f32_fp8(wv[w], false);
                f32x2 pb = __builtin_amdgcn_cvt_pk_f32_fp8(wv[w], true);
                float xa = pa[0] + dxv[2 * w],     ya = pa[1] + dyv[2 * w];
                float xb = pb[0] + dxv[2 * w + 1], yb = pb[1] + dyv[2 * w + 1];
                sacc[2 * w]     += sqrtf(xa * xa + ya * ya + EPS);
                sacc[2 * w + 1] += sqrtf(xb * xb + yb * yb + EPS);
            }
        }
#pragma unroll
        for (int j = 0; j < 8; ++j) red[tid][j] = sacc[j];
    }
    __syncthreads();
    if (tid < 64) {
        const int dgq = tid >> 3, j = tid & 7;
        float t = 0.f;
#pragma unroll
        for (int c = 0; c < 32; ++c) t += red[c * 8 + dgq][j];
        pooled[b * 256 + qd * 64 + dgq * 8 + j] = t;
    }
}

// ---------------------------------------------------------------------------
// Kernel 3 (verbatim round-1): classifier, n-dim sliced over blockIdx.y.
// ---------------------------------------------------------------------------
__global__ __launch_bounds__(256) void cls_kernel(
    const float* __restrict__ pooled,
    const float* __restrict__ w1, const float* __restrict__ b1,
    const float* __restrict__ w2, const float* __restrict__ b2,
    float* __restrict__ out)
{
    __shared__ float pl[256];
    __shared__ float part[8][32];
    __shared__ float hd[32];
    const int b = blockIdx.x, yc = blockIdx.y, tid = threadIdx.x;
    pl[tid] = pooled[b * 256 + tid] * (1.0f / 1024.0f);
    __syncthreads();
    const int hu = tid & 31, kc = tid >> 5;
    float a = 0.f;
    for (int k = kc * 32; k < kc * 32 + 32; ++k) a += pl[k] * w1[k * 32 + hu];
    part[kc][hu] = a;
    __syncthreads();
    if (tid < 32) {
        float s = b1[tid];
#pragma unroll
        for (int c = 0; c < 8; ++c) s += part[c][tid];
        hd[tid] = gelu_exact(s);
    }
    __syncthreads();
    const int n0 = yc * 250;
    const int nend = (n0 + 250 < 1000) ? n0 + 250 : 1000;
    for (int n = n0 + tid; n < nend; n += 256) {
        float s = b2[n];
#pragma unroll
        for (int k = 0; k < 32; ++k) s += hd[k] * w2[k * 1000 + n];
        out[b * 1000 + n] = s;
    }
}

// ---------------------------------------------------------------------------
extern "C" void kernel_launch(void* const* d_in, const int* in_sizes, int n_in,
                              void* d_out, int out_size, void* d_ws, size_t ws_size,
                              hipStream_t stream)
{
    const float* x       = (const float*)d_in[0];
    const float* embed_w = (const float*)d_in[1];
    const float* embed_b = (const float*)d_in[2];
    const float* mag_w1  = (const float*)d_in[3];
    const float* mag_b1  = (const float*)d_in[4];
    const float* mag_w2  = (const float*)d_in[5];
    const float* mag_b2  = (const float*)d_in[6];
    const float* ph_w1   = (const float*)d_in[7];
    const float* ph_b1   = (const float*)d_in[8];
    const float* ph_w2   = (const float*)d_in[9];
    const float* ph_b2   = (const float*)d_in[10];
    const float* cls_w1  = (const float*)d_in[11];
    const float* cls_b1  = (const float*)d_in[12];
    const float* cls_w2  = (const float*)d_in[13];
    const float* cls_b2  = (const float*)d_in[14];
    float* out = (float*)d_out;

    char* ws = (char*)d_ws;
    unsigned short* XY8 = (unsigned short*)(ws + 0);   // 33554432 B (fp8 pairs)
    _Float16* Wth = (_Float16*)(ws + 33554432);        // 262144
    _Float16* Wtl = (_Float16*)(ws + 33816576);        // 262144
    float* XMsum  = (float*)(ws + 34078720);           // 65536
    float* YMsum  = (float*)(ws + 34144256);           // 65536
    float* pooled = (float*)(ws + 34209792);           // 65536

    convertW<<<512, 256, 0, stream>>>(embed_w, Wth, Wtl, XMsum);  // zeros XMsum,YMsum,pooled (contiguous)
    gemm_embed<<<2048, 256, 0, stream>>>(x, Wth, Wtl, embed_b, XY8, XMsum, YMsum);
    tail_kernel<<<dim3(64, 4), 256, 0, stream>>>(XMsum, YMsum,
                                                 mag_w1, mag_b1, mag_w2, mag_b2,
                                                 ph_w1, ph_b1, ph_w2, ph_b2,
                                                 XY8, pooled);
    cls_kernel<<<dim3(64, 4), 256, 0, stream>>>(pooled, cls_w1, cls_b1, cls_w2, cls_b2, out);
}

// Round 8
// 205.069 us; speedup vs baseline: 3.1534x; 1.0196x over previous
//
#include <hip/hip_runtime.h>
#include <hip/hip_bf16.h>
#include <hip/hip_fp16.h>

#define EPS 1e-8f
#define PI_F 3.14159265358979323846f

typedef _Float16 half8 __attribute__((ext_vector_type(8)));
typedef float f32x4 __attribute__((ext_vector_type(4)));
typedef float f32x2 __attribute__((ext_vector_type(2)));

__device__ __forceinline__ float gelu_exact(float v) {
    return 0.5f * v * (1.0f + erff(v * 0.70710678118654752f));
}

// ---------------------------------------------------------------------------
// Kernel 1: embed GEMM (3-pass fp16 split) + fused polar transform.
// Same as round 7 (W read fp32 directly, in-register hi/lo split, W loads
// hidden under A-staging, per-m-tile mean partials) PLUS the race fix:
// waves (wm=0, wm=1) share each mean slot, so partials are combined via an
// LDS scratch reduce (wm0 parks, wm1 adds + stores once). Round-7's plain
// stores raced on exactly those slots -> absmax 2.44.
// XCD swizzle unchanged: 4 g-blocks of one m-tile co-resident on one XCD.
// ---------------------------------------------------------------------------
__global__ __launch_bounds__(256, 4) void gemm_embed(
    const float* __restrict__ x,
    const float* __restrict__ W,          // embed_w [256 k][512 col] fp32
    const float* __restrict__ bias,
    unsigned short* __restrict__ XY8,
    float* __restrict__ XMpart, float* __restrict__ YMpart)
{
    __shared__ __attribute__((aligned(16))) _Float16 Ah[4096], Al[4096];
    const int tid  = threadIdx.x;
    const int wave = tid >> 6;
    const int lane = tid & 63;
    const int wm   = wave >> 1;              // m-half of the 128 rows
    const int wn   = wave & 1;               // n-half (d 32-range)
    const int id   = blockIdx.x;
    const int xcd  = id & 7;
    const int s    = id >> 3;
    const int g    = s & 3;                  // d-range [64g, 64g+64)
    const int mt   = (s >> 2) * 8 + xcd;     // 0..511
    const int m0   = mt * 128;
    const int q    = lane >> 4, ln = lane & 15;

    // this lane's two d's and the 4 W columns (nt0=h1 d0, nt1=h1 d1,
    // nt2=h2 d0, nt3=h2 d1)
    const int d0 = g * 64 + wn * 32 + ln;
    const int d1 = d0 + 16;
    const float* wc0 = W + d0;
    const float* wc1 = W + d1;
    const float* wc2 = W + 256 + d0;
    const float* wc3 = W + 256 + d1;

    f32x4 acc[4][4];
#pragma unroll
    for (int mi = 0; mi < 4; ++mi)
#pragma unroll
        for (int nt = 0; nt < 4; ++nt)
            acc[mi][nt] = (f32x4){0.f, 0.f, 0.f, 0.f};

    for (int kt = 0; kt < 8; ++kt) {
        __syncthreads();   // barrier1: previous kt's LDS readers done
        // ---- issue W fp32 loads for this kt (drain at barrier2, so the
        //      L2 latency hides under the A-staging below) ----
        float wf0[8], wf1[8], wf2[8], wf3[8];
#pragma unroll
        for (int j = 0; j < 8; ++j) {
            const int ko = (kt * 32 + q * 8 + j) * 512;
            wf0[j] = wc0[ko];
            wf1[j] = wc1[ko];
            wf2[j] = wc2[ko];
            wf3[j] = wc3[ko];
        }
        // ---- stage A tile [128 m][32 k]: fp32 -> fp16 hi + lo residual ----
#pragma unroll
        for (int L = 0; L < 2; ++L) {
            int idx2 = L * 256 + tid;
            int r = idx2 >> 2, cq = idx2 & 3;
            const float* src = x + (size_t)(m0 + r) * 256 + kt * 32 + cq * 8;
            const float4 f0 = *(const float4*)(src);
            const float4 f1 = *(const float4*)(src + 4);
            half8 hh, ll;
            hh[0] = (_Float16)f0.x; ll[0] = (_Float16)(f0.x - (float)hh[0]);
            hh[1] = (_Float16)f0.y; ll[1] = (_Float16)(f0.y - (float)hh[1]);
            hh[2] = (_Float16)f0.z; ll[2] = (_Float16)(f0.z - (float)hh[2]);
            hh[3] = (_Float16)f0.w; ll[3] = (_Float16)(f0.w - (float)hh[3]);
            hh[4] = (_Float16)f1.x; ll[4] = (_Float16)(f1.x - (float)hh[4]);
            hh[5] = (_Float16)f1.y; ll[5] = (_Float16)(f1.y - (float)hh[5]);
            hh[6] = (_Float16)f1.z; ll[6] = (_Float16)(f1.z - (float)hh[6]);
            hh[7] = (_Float16)f1.w; ll[7] = (_Float16)(f1.w - (float)hh[7]);
            int pos = cq ^ ((r >> 1) & 3);
            *(half8*)&Ah[r * 32 + pos * 8] = hh;
            *(half8*)&Al[r * 32 + pos * 8] = ll;
        }
        __syncthreads();   // barrier2: drains x loads + W loads (aged ~free)

        // ---- in-register W split -> bh/bl (bit-identical to old Wth/Wtl) ----
        half8 bh[4], bl[4];
#pragma unroll
        for (int j = 0; j < 8; ++j) {
            _Float16 h0 = (_Float16)wf0[j];
            bh[0][j] = h0; bl[0][j] = (_Float16)(wf0[j] - (float)h0);
            _Float16 h1v = (_Float16)wf1[j];
            bh[1][j] = h1v; bl[1][j] = (_Float16)(wf1[j] - (float)h1v);
            _Float16 h2v = (_Float16)wf2[j];
            bh[2][j] = h2v; bl[2][j] = (_Float16)(wf2[j] - (float)h2v);
            _Float16 h3v = (_Float16)wf3[j];
            bh[3][j] = h3v; bl[3][j] = (_Float16)(wf3[j] - (float)h3v);
        }

        // ---- A fragments (rows wm*64 .. wm*64+63) ----
        half8 am[4];
#pragma unroll
        for (int mi = 0; mi < 4; ++mi) {
            int row = wm * 64 + mi * 16 + ln;
            am[mi] = *(const half8*)&Ah[row * 32 + (q ^ ((row >> 1) & 3)) * 8];
        }
        // pass 1: Ah*Bh
#pragma unroll
        for (int mi = 0; mi < 4; ++mi)
#pragma unroll
            for (int nt = 0; nt < 4; ++nt)
                acc[mi][nt] = __builtin_amdgcn_mfma_f32_16x16x32_f16(am[mi], bh[nt], acc[mi][nt], 0, 0, 0);
        // pass 2: Ah*Bl
#pragma unroll
        for (int mi = 0; mi < 4; ++mi)
#pragma unroll
            for (int nt = 0; nt < 4; ++nt)
                acc[mi][nt] = __builtin_amdgcn_mfma_f32_16x16x32_f16(am[mi], bl[nt], acc[mi][nt], 0, 0, 0);
        // pass 3: Al*Bh
#pragma unroll
        for (int mi = 0; mi < 4; ++mi) {
            int row = wm * 64 + mi * 16 + ln;
            half8 alv = *(const half8*)&Al[row * 32 + (q ^ ((row >> 1) & 3)) * 8];
#pragma unroll
            for (int nt = 0; nt < 4; ++nt)
                acc[mi][nt] = __builtin_amdgcn_mfma_f32_16x16x32_f16(alv, bh[nt], acc[mi][nt], 0, 0, 0);
        }
    }

    // ---- epilogue ----
    // acc[mi][0]=h1(d0), acc[mi][1]=h1(d1), acc[mi][2]=h2(d0), acc[mi][3]=h2(d1)
    // C/D layout: col = lane&15, row = (lane>>4)*4 + reg  [m89 verified]
    const float b1_0 = bias[d0],       b1_1 = bias[d1];
    const float b2_0 = bias[256 + d0], b2_1 = bias[256 + d1];
    float sx0 = 0.f, sy0 = 0.f, sx1 = 0.f, sy1 = 0.f;
#pragma unroll
    for (int mi = 0; mi < 4; ++mi) {
#pragma unroll
        for (int i = 0; i < 4; ++i) {
            const int row = m0 + wm * 64 + mi * 16 + q * 4 + i;
            {
                const float h1 = acc[mi][0][i] + b1_0;
                const float h2 = acc[mi][2][i] + b2_0;
                const float rr = fabsf(h1) + 0.1f;
                float sv, cv;
                __sincosf(PI_F * h2, &sv, &cv);
                const float xc = rr * cv, yc = rr * sv;
                int pk = __builtin_amdgcn_cvt_pk_fp8_f32(xc, yc, 0, false);
                XY8[(size_t)row * 256 + d0] = (unsigned short)pk;
                sx0 += xc; sy0 += yc;
            }
            {
                const float h1 = acc[mi][1][i] + b1_1;
                const float h2 = acc[mi][3][i] + b2_1;
                const float rr = fabsf(h1) + 0.1f;
                float sv, cv;
                __sincosf(PI_F * h2, &sv, &cv);
                const float xc = rr * cv, yc = rr * sv;
                int pk = __builtin_amdgcn_cvt_pk_fp8_f32(xc, yc, 0, false);
                XY8[(size_t)row * 256 + d1] = (unsigned short)pk;
                sx1 += xc; sy1 += yc;
            }
        }
    }
    // intra-wave reduce over q (rows of this wm-half)
    sx0 += __shfl_down(sx0, 32); sx0 += __shfl_down(sx0, 16);
    sy0 += __shfl_down(sy0, 32); sy0 += __shfl_down(sy0, 16);
    sx1 += __shfl_down(sx1, 32); sx1 += __shfl_down(sx1, 16);
    sy1 += __shfl_down(sy1, 32); sy1 += __shfl_down(sy1, 16);

    // cross-wave (wm) reduce via LDS scratch (Ah is dead now), single store
    // per (mt,d) slot. Round-7 bug: wm=0 and wm=1 waves raced on these slots.
    __syncthreads();                       // all MFMA LDS reads done
    float* sc = (float*)Ah;                // 256 floats scratch
    if (wm == 0 && lane < 16) {
        sc[wn * 64 + ln]            = sx0;
        sc[wn * 64 + 16 + ln]       = sx1;
        sc[128 + wn * 64 + ln]      = sy0;
        sc[128 + wn * 64 + 16 + ln] = sy1;
    }
    __syncthreads();
    if (wm == 1 && lane < 16) {
        XMpart[mt * 256 + d0] = sx0 + sc[wn * 64 + ln];
        XMpart[mt * 256 + d1] = sx1 + sc[wn * 64 + 16 + ln];
        YMpart[mt * 256 + d0] = sy0 + sc[128 + wn * 64 + ln];
        YMpart[mt * 256 + d1] = sy1 + sc[128 + wn * 64 + 16 + ln];
    }
}

// ---------------------------------------------------------------------------
// Kernel 2: fused part-reduce + layers + pool. Grid (64 b, 8 d-eighths);
// each block EXCLUSIVELY owns (b, 32 d's): full 512-block layers parallelism.
// Means: 8 per-m-tile partials butterfly-summed across the 8-lane sub-group.
// ---------------------------------------------------------------------------
__global__ __launch_bounds__(256) void tail_kernel(
    const float* __restrict__ XMpart, const float* __restrict__ YMpart,
    const float* __restrict__ mw1, const float* __restrict__ mb1,
    const float* __restrict__ mw2, const float* __restrict__ mb2,
    const float* __restrict__ pw1, const float* __restrict__ pb1,
    const float* __restrict__ pw2, const float* __restrict__ pb2,
    const unsigned short* __restrict__ XY8,
    float* __restrict__ pooled)
{
    __shared__ float s_mw1[256], s_mb1[256], s_mw2[256], s_mb2[8];
    __shared__ float s_pw1[512], s_pb1[256], s_pw2[512], s_pb2[16];
    __shared__ float dxl[32], dyl[32];
    __shared__ float red[256][9];
    const int b = blockIdx.x, q8 = blockIdx.y, tid = threadIdx.x;

    s_mw1[tid] = mw1[tid]; s_mb1[tid] = mb1[tid];
    s_mw2[tid] = mw2[tid]; s_pb1[tid] = pb1[tid];
    s_pw1[tid] = pw1[tid]; s_pw1[256 + tid] = pw1[256 + tid];
    s_pw2[tid] = pw2[tid]; s_pw2[256 + tid] = pw2[256 + tid];
    if (tid < 8)  s_mb2[tid] = mb2[tid];
    if (tid < 16) s_pb2[tid] = pb2[tid];
    __syncthreads();

    // ---- layers phase: 32 d x 8 subs = 256 threads, one sweep ----
    {
        const int sub  = tid & 7;                  // k-eighth AND part index
        const int dloc = tid >> 3;                 // 0..31
        const int d    = q8 * 32 + dloc;
        float xm = XMpart[(b * 8 + sub) * 256 + d];
        float ym = YMpart[(b * 8 + sub) * 256 + d];
        xm += __shfl_xor(xm, 1); xm += __shfl_xor(xm, 2); xm += __shfl_xor(xm, 4);
        ym += __shfl_xor(ym, 1); ym += __shfl_xor(ym, 2); ym += __shfl_xor(ym, 4);
        xm *= (1.0f / 1024.0f);
        ym *= (1.0f / 1024.0f);
        float dxa = 0.f, dya = 0.f;
#pragma unroll 1
        for (int i = 0; i < 8; ++i) {
            float r2    = xm * xm + ym * ym;
            float r_agg = sqrtf(r2 + EPS);
            float hyp   = sqrtf(r2);
            float inv   = hyp > 0.f ? 1.0f / hyp : 0.f;
            float st    = ym * inv;
            float ct    = hyp > 0.f ? xm * inv : 1.0f;
            float log_r = logf(r_agg + EPS);
            float lr = 0.f, p0 = 0.f, p1 = 0.f;
#pragma unroll
            for (int k4 = 0; k4 < 4; ++k4) {
                int k = sub * 4 + k4;
                float hm = gelu_exact(log_r * s_mw1[i * 32 + k] + s_mb1[i * 32 + k]);
                lr += hm * s_mw2[i * 32 + k];
                float hp = gelu_exact(st * s_pw1[i * 64 + k] + ct * s_pw1[i * 64 + 32 + k] + s_pb1[i * 32 + k]);
                p0 += hp * s_pw2[i * 64 + 2 * k + 0];
                p1 += hp * s_pw2[i * 64 + 2 * k + 1];
            }
            lr += __shfl_xor(lr, 1); lr += __shfl_xor(lr, 2); lr += __shfl_xor(lr, 4);
            p0 += __shfl_xor(p0, 1); p0 += __shfl_xor(p0, 2); p0 += __shfl_xor(p0, 4);
            p1 += __shfl_xor(p1, 1); p1 += __shfl_xor(p1, 2); p1 += __shfl_xor(p1, 4);
            lr += s_mb2[i];
            p0 += s_pb2[i * 2 + 0];
            p1 += s_pb2[i * 2 + 1];
            float r_trans = expf(lr);
            float hp2  = sqrtf(p0 * p0 + p1 * p1);
            float invp = hp2 > 0.f ? 1.0f / hp2 : 0.f;
            float ctt  = hp2 > 0.f ? p1 * invp : 1.0f;
            float stt  = p0 * invp;
            float dx = r_trans * ctt;
            float dy = r_trans * stt;
            dxa += dx; dya += dy; xm += dx; ym += dy;
        }
        if (sub == 0) { dxl[dloc] = dxa; dyl[dloc] = dya; }
    }
    __syncthreads();

    // ---- pool phase: 32 d x 1024 s per block ----
    {
        const int dg = tid & 3;            // d-octet: d = q8*32 + dg*8 ..+7
        const int sh = tid >> 2;           // 0..63: rows sh*16 .. sh*16+15
        const int d0 = q8 * 32 + dg * 8;
        float dxv[8], dyv[8], sacc[8];
#pragma unroll
        for (int j = 0; j < 8; ++j) {
            dxv[j] = dxl[dg * 8 + j];
            dyv[j] = dyl[dg * 8 + j];
            sacc[j] = 0.f;
        }
        const size_t base = ((size_t)b * 1024 + sh * 16) * 256 + d0;
#pragma unroll 4
        for (int i = 0; i < 16; ++i) {
            const int4 v = *(const int4*)(XY8 + base + (size_t)i * 256);
            const int wv[4] = {v.x, v.y, v.z, v.w};
#pragma unroll
            for (int w = 0; w < 4; ++w) {
                f32x2 pa = __builtin_amdgcn_cvt_pk_f32_fp8(wv[w], false);
                f32x2 pb = __builtin_amdgcn_cvt_pk_f32_fp8(wv[w], true);
                float xa = pa[0] + dxv[2 * w],     ya = pa[1] + dyv[2 * w];
                float xb = pb[0] + dxv[2 * w + 1], yb = pb[1] + dyv[2 * w + 1];
                sacc[2 * w]     += sqrtf(xa * xa + ya * ya + EPS);
                sacc[2 * w + 1] += sqrtf(xb * xb + yb * yb + EPS);
            }
        }
#pragma unroll
        for (int j = 0; j < 8; ++j) red[tid][j] = sacc[j];
    }
    __syncthreads();
    if (tid < 32) {
        const int dgq = tid >> 3, j = tid & 7;
        float t = 0.f;
#pragma unroll
        for (int c = 0; c < 64; ++c) t += red[c * 4 + dgq][j];
        pooled[b * 256 + q8 * 32 + dgq * 8 + j] = t;
    }
}

// ---------------------------------------------------------------------------
// Kernel 3 (verbatim): classifier, n-dim sliced over blockIdx.y.
// ---------------------------------------------------------------------------
__global__ __launch_bounds__(256) void cls_kernel(
    const float* __restrict__ pooled,
    const float* __restrict__ w1, const float* __restrict__ b1,
    const float* __restrict__ w2, const float* __restrict__ b2,
    float* __restrict__ out)
{
    __shared__ float pl[256];
    __shared__ float part[8][32];
    __shared__ float hd[32];
    const int b = blockIdx.x, yc = blockIdx.y, tid = threadIdx.x;
    pl[tid] = pooled[b * 256 + tid] * (1.0f / 1024.0f);
    __syncthreads();
    const int hu = tid & 31, kc = tid >> 5;
    float a = 0.f;
    for (int k = kc * 32; k < kc * 32 + 32; ++k) a += pl[k] * w1[k * 32 + hu];
    part[kc][hu] = a;
    __syncthreads();
    if (tid < 32) {
        float s = b1[tid];
#pragma unroll
        for (int c = 0; c < 8; ++c) s += part[c][tid];
        hd[tid] = gelu_exact(s);
    }
    __syncthreads();
    const int n0 = yc * 250;
    const int nend = (n0 + 250 < 1000) ? n0 + 250 : 1000;
    for (int n = n0 + tid; n < nend; n += 256) {
        float s = b2[n];
#pragma unroll
        for (int k = 0; k < 32; ++k) s += hd[k] * w2[k * 1000 + n];
        out[b * 1000 + n] = s;
    }
}

// ---------------------------------------------------------------------------
extern "C" void kernel_launch(void* const* d_in, const int* in_sizes, int n_in,
                              void* d_out, int out_size, void* d_ws, size_t ws_size,
                              hipStream_t stream)
{
    const float* x       = (const float*)d_in[0];
    const float* embed_w = (const float*)d_in[1];
    const float* embed_b = (const float*)d_in[2];
    const float* mag_w1  = (const float*)d_in[3];
    const float* mag_b1  = (const float*)d_in[4];
    const float* mag_w2  = (const float*)d_in[5];
    const float* mag_b2  = (const float*)d_in[6];
    const float* ph_w1   = (const float*)d_in[7];
    const float* ph_b1   = (const float*)d_in[8];
    const float* ph_w2   = (const float*)d_in[9];
    const float* ph_b2   = (const float*)d_in[10];
    const float* cls_w1  = (const float*)d_in[11];
    const float* cls_b1  = (const float*)d_in[12];
    const float* cls_w2  = (const float*)d_in[13];
    const float* cls_b2  = (const float*)d_in[14];
    float* out = (float*)d_out;

    char* ws = (char*)d_ws;
    unsigned short* XY8 = (unsigned short*)(ws + 0);   // 33554432 B (fp8 pairs)
    float* XMpart = (float*)(ws + 33554432);           // 512 KB [512 mt][256 d]
    float* YMpart = (float*)(ws + 34078720);           // 512 KB
    float* pooled = (float*)(ws + 34603008);           // 64 KB

    gemm_embed<<<2048, 256, 0, stream>>>(x, embed_w, embed_b, XY8, XMpart, YMpart);
    tail_kernel<<<dim3(64, 8), 256, 0, stream>>>(XMpart, YMpart,
                                                 mag_w1, mag_b1, mag_w2, mag_b2,
                                                 ph_w1, ph_b1, ph_w2, ph_b2,
                                                 XY8, pooled);
    cls_kernel<<<dim3(64, 4), 256, 0, stream>>>(pooled, cls_w1, cls_b1, cls_w2, cls_b2, out);
}